// Round 7
// baseline (456.975 us; speedup 1.0000x reference)
//
#include <hip/hip_runtime.h>
#include <hip/hip_bf16.h>
#include <stdint.h>

// ScaledDotProductAttention S=4096 D=1024 fp32.
// cvt->bf16 (+rowsum/cnt zero) | G1 QKV BK=64 (V stored transposed) | G2 S=exp(Q.K^T)
// BK=64, rowsum atomics, XCD swizzle | G3 O-partials BK=64 split-K=4, XCD-partitioned
// decode, last-finisher fuses the cross-split reduction into out (counter+threadfence).
// R7 changes: (1) G3 XCD-partitioned block decode (R6: FETCH 135 MB vs 42 unique, 3.59
// TB/s HBM = thrash; each XCD now owns z x m-half: A 4MB + B 2MB footprint); (2)
// reduce_out kernel fused into G3 epilogue via per-tile completion counters (kills an
// 11 us kernel + ~10 us launch boundary).

typedef __bf16 bf16_t;
typedef __bf16 bf16x4 __attribute__((ext_vector_type(4)));
typedef __bf16 bf16x8 __attribute__((ext_vector_type(8)));
typedef float f32x4 __attribute__((ext_vector_type(4)));

#define AS1 __attribute__((address_space(1)))
#define AS3 __attribute__((address_space(3)))

__device__ __forceinline__ void async_ld16(const void* g, void* l) {
  // global -> LDS DMA, 16B/lane; LDS dest is wave-uniform base + lane*16 by HW rule.
  __builtin_amdgcn_global_load_lds((AS1 void*)g, (AS3 void*)l, 16, 0, 0);
}

// MODE 0: QKV epilogue (bias; Q scaled 1/32; V transposed).
// MODE 1: S epilogue: store exp(acc) bf16 ldc=4096, atomicAdd fp32 row sums. XCD swizzle.
// MODE 2: O epilogue (split-K=4, 1D grid 1024, XCD-partitioned decode): z<3 -> bf16
//         partial to o_z; z==3 -> fp32 to fout; all pre-scaled by 1/rowsum. Last
//         finisher per tile (cnt) sums the 4 partials into fout.
template <int MODE, int BN, int BK>
__global__ __launch_bounds__(256, 2) void gemm_k(
    const bf16_t* __restrict__ A, const bf16_t* __restrict__ B, const int ld,
    const int Klen,
    bf16_t* __restrict__ o0, bf16_t* __restrict__ o1, bf16_t* __restrict__ o2,
    const float* __restrict__ b0, const float* __restrict__ b1,
    const float* __restrict__ b2, float* __restrict__ fout,
    float* __restrict__ rowsum, int* __restrict__ cnt) {
  constexpr int NF = BN / 32;   // n-frags per wave
  constexpr int KS = BK / 32;   // mfma k-steps per tile
  constexpr int CH = BK / 8;    // 16B chunks per LDS row
  constexpr int RS = 256 / CH;  // rows staged per DMA round
  __shared__ bf16_t As[128 * BK];
  __shared__ bf16_t Bs[BN * BK];

  const int t = threadIdx.x;
  const int lane = t & 63;
  const int wave = t >> 6;
  const int wm = wave >> 1;
  const int wn = wave & 1;
  const int q = lane >> 4;
  const int l16 = lane & 15;
  const int wnoff = wn * (BN / 2);

  int m0, n0, k0, zz = 0, tileId = 0;
  if constexpr (MODE == 1) {
    // XCD-aware swizzle (grid 32x32): xcd = bid&7 owns a 16m x 8n region (bijective).
    const int bid = blockIdx.y * 32 + blockIdx.x;
    const int xcd = bid & 7, sl = bid >> 3;  // sl in 0..127
    m0 = ((xcd >> 2) * 16 + (sl >> 3)) * 128;
    n0 = ((xcd & 3) * 8 + (sl & 7)) * BN;
    k0 = 0;
  } else if constexpr (MODE == 2) {
    // XCD partition (1D grid 1024, round-robin bid->XCD assumed): each XCD owns one
    // (z, m-half): 16 m-tiles x 8 n-tiles = 128 blocks; L2 footprint A 4MB + B 2MB.
    const int lin = blockIdx.x;
    const int xcd = lin & 7;
    const int s = lin >> 3;             // 0..127
    zz = xcd >> 1;                      // split index 0..3
    const int mt = (xcd & 1) * 16 + (s >> 3);
    const int nt = s & 7;
    m0 = mt * 128;
    n0 = nt * 128;
    k0 = zz * Klen;
    tileId = mt * 8 + nt;
  } else {
    n0 = blockIdx.x * BN;
    m0 = blockIdx.y * 128;
    k0 = blockIdx.z * Klen;
  }

  const f32x4 zero4 = {0.f, 0.f, 0.f, 0.f};
  f32x4 acc[4][NF];
#pragma unroll
  for (int i = 0; i < 4; ++i)
#pragma unroll
    for (int j = 0; j < NF; ++j) acc[i][j] = zero4;

  // Staging: thread t -> row srow = t/CH, LDS slot t%CH; GLOBAL chunk = slot ^ swz(srow)
  // so the read side inverts with xf = swz(row), a per-lane constant on rows 16a+l16:
  //   BK=32: swz(r) = (r>>1)&3 = (l16>>1)&3   (R2-verified: conflicts 4.19M -> 0)
  //   BK=64: swz(r) = r&7     = l16&7         (R5-proven; 2 lanes/bank = free)
  const int srow = t / CH;
  const int schunk =
      (t % CH) ^ ((BK == 32) ? ((srow >> 1) & 3) : (srow & 7));
  const bf16_t* Ab = A + (size_t)(m0 + srow) * ld + k0 + schunk * 8;
  const bf16_t* Bb = B + (size_t)(n0 + srow) * ld + k0 + schunk * 8;
  bf16_t* Asl = As + t * 8;
  bf16_t* Bsl = Bs + t * 8;

  const int xf = (BK == 32) ? ((l16 >> 1) & 3) : (l16 & 7);
  const int ar = wm * 64 + l16;
  const int br = wnoff + l16;

  for (int kt = 0; kt < Klen; kt += BK) {
#pragma unroll
    for (int rr = 0; rr < 128 / RS; ++rr)
      async_ld16(Ab + kt + (size_t)(rr * RS) * ld, Asl + rr * RS * BK);
#pragma unroll
    for (int rr = 0; rr < BN / RS; ++rr)
      async_ld16(Bb + kt + (size_t)(rr * RS) * ld, Bsl + rr * RS * BK);
    __syncthreads();

#pragma unroll
    for (int s = 0; s < KS; ++s) {
      bf16x8 fa[4], fb[NF];
#pragma unroll
      for (int im = 0; im < 4; ++im)
        fa[im] = *(const bf16x8*)(As + (ar + im * 16) * BK +
                                  (((s * 4 + q) ^ xf) * 8));
#pragma unroll
      for (int j = 0; j < NF; ++j)
        fb[j] = *(const bf16x8*)(Bs + (br + j * 16) * BK +
                                 (((s * 4 + q) ^ xf) * 8));
#pragma unroll
      for (int im = 0; im < 4; ++im)
#pragma unroll
        for (int j = 0; j < NF; ++j)
          acc[im][j] = __builtin_amdgcn_mfma_f32_16x16x32_bf16(
              fa[im], fb[j], acc[im][j], 0, 0, 0);
    }
    __syncthreads();
  }

  // C/D layout: col = lane&15, row = quad*4 + reg (m89/m91-verified).
  const int mBase = m0 + wm * 64 + q * 4;

  if constexpr (MODE == 0) {
    const int sel = n0 >> 10;  // 0=Q 1=K 2=V
    const int nl0 = (n0 & 1023) + wnoff + l16;
    const float* bias = (sel == 0) ? b0 : ((sel == 1) ? b1 : b2);
    const float sc = (sel == 0) ? 0.03125f : 1.0f;  // 1/sqrt(1024) folded into Q
#pragma unroll
    for (int j = 0; j < NF; ++j) {
      const int nl = nl0 + j * 16;
      const float bb = bias[nl];
#pragma unroll
      for (int im = 0; im < 4; ++im) {
        const int mr = mBase + im * 16;
        if (sel < 2) {
          bf16_t* dst = (sel == 0) ? o0 : o1;
#pragma unroll
          for (int r = 0; r < 4; ++r)
            dst[(size_t)(mr + r) * 1024 + nl] =
                (bf16_t)((acc[im][j][r] + bb) * sc);
        } else {
          bf16x4 v;  // V^T[d][key]: 4 regs = 4 consecutive keys -> packed 8B store
#pragma unroll
          for (int r = 0; r < 4; ++r) v[r] = (bf16_t)(acc[im][j][r] + bb);
          *(bf16x4*)(o2 + (size_t)nl * 4096 + mr) = v;
        }
      }
    }
  } else if constexpr (MODE == 1) {
    float ps[4][4];
#pragma unroll
    for (int im = 0; im < 4; ++im)
#pragma unroll
      for (int r = 0; r < 4; ++r) ps[im][r] = 0.f;
#pragma unroll
    for (int j = 0; j < NF; ++j) {
      const int n = n0 + wnoff + j * 16 + l16;
#pragma unroll
      for (int im = 0; im < 4; ++im) {
        const int mr = mBase + im * 16;
#pragma unroll
        for (int r = 0; r < 4; ++r) {
          const float e = __expf(acc[im][j][r]);
          ps[im][r] += e;
          o0[(size_t)(mr + r) * 4096 + n] = (bf16_t)e;
        }
      }
    }
#pragma unroll
    for (int im = 0; im < 4; ++im)
#pragma unroll
      for (int r = 0; r < 4; ++r) {
        float v = ps[im][r];
        v += __shfl_xor(v, 1);
        v += __shfl_xor(v, 2);
        v += __shfl_xor(v, 4);
        v += __shfl_xor(v, 8);
        ps[im][r] = v;
      }
    if (l16 == 0) {
#pragma unroll
      for (int im = 0; im < 4; ++im)
#pragma unroll
        for (int r = 0; r < 4; ++r)
          atomicAdd(rowsum + mBase + im * 16 + r, ps[im][r]);
    }
  } else {
    float inv[4][4];
#pragma unroll
    for (int im = 0; im < 4; ++im)
#pragma unroll
      for (int r = 0; r < 4; ++r)
        inv[im][r] = 1.0f / rowsum[mBase + im * 16 + r];
    if (zz < 3) {  // bf16 partial (normalized); partials over splits sum to O
      bf16_t* pp = (zz == 0) ? o0 : ((zz == 1) ? o1 : o2);
#pragma unroll
      for (int im = 0; im < 4; ++im) {
        const int mr = mBase + im * 16;
#pragma unroll
        for (int j = 0; j < NF; ++j) {
          const int n = n0 + wnoff + j * 16 + l16;
#pragma unroll
          for (int r = 0; r < 4; ++r)
            pp[(size_t)(mr + r) * 1024 + n] =
                (bf16_t)(acc[im][j][r] * inv[im][r]);
        }
      }
    } else {  // z==3: fp32 partial straight into d_out
#pragma unroll
      for (int im = 0; im < 4; ++im) {
        const int mr = mBase + im * 16;
#pragma unroll
        for (int j = 0; j < NF; ++j) {
          const int n = n0 + wnoff + j * 16 + l16;
#pragma unroll
          for (int r = 0; r < 4; ++r)
            fout[(size_t)(mr + r) * 1024 + n] = acc[im][j][r] * inv[im][r];
        }
      }
    }
    // Fused cross-split reduction: last finisher of the 4 z-blocks sums partials.
    __threadfence();   // release: this block's partial visible device-wide
    __syncthreads();   // all threads' stores fenced before the count
    __shared__ int lastFlag;
    if (t == 0) lastFlag = (atomicAdd(cnt + tileId, 1) == 3) ? 1 : 0;
    __syncthreads();
    if (lastFlag) {
      __threadfence();  // acquire: other splits' partials visible
      const int rr2 = t >> 1, cb = (t & 1) * 64;  // 128 rows x 2 col-halves
      const size_t base = (size_t)(m0 + rr2) * 1024 + n0 + cb;
#pragma unroll
      for (int kk = 0; kk < 8; ++kk) {
        const size_t idx = base + kk * 8;
        const bf16x8 a = *(const bf16x8*)(o0 + idx);
        const bf16x8 b = *(const bf16x8*)(o1 + idx);
        const bf16x8 c = *(const bf16x8*)(o2 + idx);
        float4 lo = *(const float4*)(fout + idx);
        float4 hi = *(const float4*)(fout + idx + 4);
        lo.x += (float)a[0] + (float)b[0] + (float)c[0];
        lo.y += (float)a[1] + (float)b[1] + (float)c[1];
        lo.z += (float)a[2] + (float)b[2] + (float)c[2];
        lo.w += (float)a[3] + (float)b[3] + (float)c[3];
        hi.x += (float)a[4] + (float)b[4] + (float)c[4];
        hi.y += (float)a[5] + (float)b[5] + (float)c[5];
        hi.z += (float)a[6] + (float)b[6] + (float)c[6];
        hi.w += (float)a[7] + (float)b[7] + (float)c[7];
        *(float4*)(fout + idx) = lo;
        *(float4*)(fout + idx + 4) = hi;
      }
    }
  }
}

// Converts X|Wq|Wk|Wv to bf16; last 17 blocks zero rowsum (4096 f32) + cnt (256 i32).
__global__ __launch_bounds__(256) void cvt_all(
    const float* __restrict__ X, const float* __restrict__ Wq,
    const float* __restrict__ Wk, const float* __restrict__ Wv,
    bf16_t* __restrict__ Xb, bf16_t* __restrict__ Wb,
    float* __restrict__ rowsum) {
  int i = blockIdx.x * 256 + threadIdx.x;  // float4 index
  if (i >= 1835008) {                      // 7168 blocks of cvt work
    rowsum[i - 1835008] = 0.f;             // 17 blocks x 256 = 4352 words
    return;
  }
  const float* src;
  bf16_t* dst;
  int off;
  if (i < 1048576) {
    src = X; dst = Xb; off = i;
  } else {
    const int w = i - 1048576;
    const int sel = w >> 18;
    off = w & 0x3FFFF;
    src = (sel == 0) ? Wq : ((sel == 1) ? Wk : Wv);
    dst = Wb + (size_t)sel * (1024 * 1024);
  }
  const float4 v = ((const float4*)src)[off];
  bf16x4 o;
  o[0] = (bf16_t)v.x; o[1] = (bf16_t)v.y; o[2] = (bf16_t)v.z; o[3] = (bf16_t)v.w;
  ((bf16x4*)dst)[off] = o;
}

extern "C" void kernel_launch(void* const* d_in, const int* in_sizes, int n_in,
                              void* d_out, int out_size, void* d_ws,
                              size_t ws_size, hipStream_t stream) {
  const int S = 4096, D = 1024;
  const float* X  = (const float*)d_in[0];
  const float* Wq = (const float*)d_in[1];
  const float* bq = (const float*)d_in[2];
  const float* Wk = (const float*)d_in[3];
  const float* bk = (const float*)d_in[4];
  const float* Wv = (const float*)d_in[5];
  const float* bv = (const float*)d_in[6];
  float* out = (float*)d_out;

  // ws layout (70 MB bf16 + 17 KB fp32/int). G3 split-K=4 partials reuse dead
  // regions: Xb (dead after G1), Qb, Kb (dead after G2); z=3 goes to d_out.
  bf16_t* Xb = (bf16_t*)d_ws;            // [4096][1024]
  bf16_t* Wb = Xb + (size_t)S * D;       // [3072][1024]
  bf16_t* Qb = Wb + (size_t)3 * D * D;   // [4096][1024], pre-scaled by 1/32
  bf16_t* Kb = Qb + (size_t)S * D;       // [4096][1024]
  bf16_t* Vt = Kb + (size_t)S * D;       // [1024][4096]  V transposed
  bf16_t* Sc = Vt + (size_t)D * S;       // [4096][4096]  exp(scores)
  float* rowsum = (float*)(Sc + (size_t)S * S);  // [4096]
  int* cnt = (int*)(rowsum + S);         // [256] split-K completion counters

  cvt_all<<<7185, 256, 0, stream>>>(X, Wq, Wk, Wv, Xb, Wb, rowsum);

  // G1: QKV = Xb @ Wb^T + bias  (M=4096, N=3072, K=1024), BK=64, grid 768 (3/CU)
  gemm_k<0, 128, 64><<<dim3(3 * D / 128, S / 128), 256, 0, stream>>>(
      Xb, Wb, D, D, Qb, Kb, Vt, bq, bk, bv, nullptr, nullptr, nullptr);
  // G2: Sc = exp(Qb @ Kb^T), rowsum partials  (M=N=4096, K=1024), BK=64, grid 1024
  gemm_k<1, 128, 64><<<dim3(S / 128, S / 128), 256, 0, stream>>>(
      Qb, Kb, D, D, Sc, nullptr, nullptr, nullptr, nullptr, nullptr, nullptr,
      rowsum, nullptr);
  // G3: O = (Sc @ Vt^T)/rowsum, K split 4x1024, 1D grid 1024, fused final reduce
  gemm_k<2, 128, 64><<<1024, 256, 0, stream>>>(
      Sc, Vt, S, S / 4, Xb, Qb, Kb, nullptr, nullptr, nullptr, out, rowsum,
      cnt);
}

// Round 8
// 206.898 us; speedup vs baseline: 2.2087x; 2.2087x over previous
//
#include <hip/hip_runtime.h>
#include <hip/hip_bf16.h>
#include <stdint.h>

// ScaledDotProductAttention S=4096 D=1024 fp32.
// cvt->bf16 (+rowsum zero) | G1 QKV BK=64 (V stored transposed) | G2 S=exp(Q.K^T) BK=64,
// rowsum atomics, XCD swizzle | G3 O-partials BK=64 split-K=4, XCD-partitioned decode |
// reduce_out sums partials -> fp32 out.
// R8 = R6 + G3 XCD-partitioned decode (R7-verified: FETCH 135->50 MB), with R7's fused
// cross-split reduction REVERTED: its __threadfence() per block = L2 writeback+invalidate
// on non-coherent XCD L2s -> 1024 L2 flushes, G3 went 50->350 us (MfmaUtil 3.8%, all
// pipes idle = miss-latency-bound). Separate reduce kernel + boundary is cheaper.

typedef __bf16 bf16_t;
typedef __bf16 bf16x4 __attribute__((ext_vector_type(4)));
typedef __bf16 bf16x8 __attribute__((ext_vector_type(8)));
typedef float f32x4 __attribute__((ext_vector_type(4)));

#define AS1 __attribute__((address_space(1)))
#define AS3 __attribute__((address_space(3)))

__device__ __forceinline__ void async_ld16(const void* g, void* l) {
  // global -> LDS DMA, 16B/lane; LDS dest is wave-uniform base + lane*16 by HW rule.
  __builtin_amdgcn_global_load_lds((AS1 void*)g, (AS3 void*)l, 16, 0, 0);
}

// MODE 0: QKV epilogue (bias; Q scaled 1/32; V transposed).
// MODE 1: S epilogue: store exp(acc) bf16 ldc=4096, atomicAdd fp32 row sums. XCD swizzle.
// MODE 2: O epilogue (split-K=4, 1D grid 1024, XCD-partitioned decode): z<3 -> bf16
//         partial to o_z; z==3 -> fp32 to fout; all pre-scaled by 1/rowsum.
template <int MODE, int BN, int BK>
__global__ __launch_bounds__(256, 2) void gemm_k(
    const bf16_t* __restrict__ A, const bf16_t* __restrict__ B, const int ld,
    const int Klen,
    bf16_t* __restrict__ o0, bf16_t* __restrict__ o1, bf16_t* __restrict__ o2,
    const float* __restrict__ b0, const float* __restrict__ b1,
    const float* __restrict__ b2, float* __restrict__ fout,
    float* __restrict__ rowsum) {
  constexpr int NF = BN / 32;   // n-frags per wave
  constexpr int KS = BK / 32;   // mfma k-steps per tile
  constexpr int CH = BK / 8;    // 16B chunks per LDS row
  constexpr int RS = 256 / CH;  // rows staged per DMA round
  __shared__ bf16_t As[128 * BK];
  __shared__ bf16_t Bs[BN * BK];

  const int t = threadIdx.x;
  const int lane = t & 63;
  const int wave = t >> 6;
  const int wm = wave >> 1;
  const int wn = wave & 1;
  const int q = lane >> 4;
  const int l16 = lane & 15;
  const int wnoff = wn * (BN / 2);

  int m0, n0, k0, zz = 0;
  if constexpr (MODE == 1) {
    // XCD-aware swizzle (grid 32x32): xcd = bid&7 owns a 16m x 8n region (bijective).
    const int bid = blockIdx.y * 32 + blockIdx.x;
    const int xcd = bid & 7, sl = bid >> 3;  // sl in 0..127
    m0 = ((xcd >> 2) * 16 + (sl >> 3)) * 128;
    n0 = ((xcd & 3) * 8 + (sl & 7)) * BN;
    k0 = 0;
  } else if constexpr (MODE == 2) {
    // XCD partition (1D grid 1024, round-robin bid->XCD heuristic): each XCD owns one
    // (z, m-half): 16 m-tiles x 8 n-tiles = 128 blocks; L2 footprint A 4MB + B 2MB.
    // Perf heuristic only -- correctness independent of actual XCD assignment.
    const int lin = blockIdx.x;
    const int xcd = lin & 7;
    const int s = lin >> 3;             // 0..127
    zz = xcd >> 1;                      // split index 0..3
    const int mt = (xcd & 1) * 16 + (s >> 3);
    const int nt = s & 7;
    m0 = mt * 128;
    n0 = nt * 128;
    k0 = zz * Klen;
  } else {
    n0 = blockIdx.x * BN;
    m0 = blockIdx.y * 128;
    k0 = blockIdx.z * Klen;
  }

  const f32x4 zero4 = {0.f, 0.f, 0.f, 0.f};
  f32x4 acc[4][NF];
#pragma unroll
  for (int i = 0; i < 4; ++i)
#pragma unroll
    for (int j = 0; j < NF; ++j) acc[i][j] = zero4;

  // Staging: thread t -> row srow = t/CH, LDS slot t%CH; GLOBAL chunk = slot ^ swz(srow)
  // so the read side inverts with xf = swz(row), a per-lane constant on rows 16a+l16:
  //   BK=32: swz(r) = (r>>1)&3 = (l16>>1)&3   (R2-verified: conflicts 4.19M -> 0)
  //   BK=64: swz(r) = r&7     = l16&7         (R5-proven; 2 lanes/bank = free)
  const int srow = t / CH;
  const int schunk =
      (t % CH) ^ ((BK == 32) ? ((srow >> 1) & 3) : (srow & 7));
  const bf16_t* Ab = A + (size_t)(m0 + srow) * ld + k0 + schunk * 8;
  const bf16_t* Bb = B + (size_t)(n0 + srow) * ld + k0 + schunk * 8;
  bf16_t* Asl = As + t * 8;
  bf16_t* Bsl = Bs + t * 8;

  const int xf = (BK == 32) ? ((l16 >> 1) & 3) : (l16 & 7);
  const int ar = wm * 64 + l16;
  const int br = wnoff + l16;

  for (int kt = 0; kt < Klen; kt += BK) {
#pragma unroll
    for (int rr = 0; rr < 128 / RS; ++rr)
      async_ld16(Ab + kt + (size_t)(rr * RS) * ld, Asl + rr * RS * BK);
#pragma unroll
    for (int rr = 0; rr < BN / RS; ++rr)
      async_ld16(Bb + kt + (size_t)(rr * RS) * ld, Bsl + rr * RS * BK);
    __syncthreads();

#pragma unroll
    for (int s = 0; s < KS; ++s) {
      bf16x8 fa[4], fb[NF];
#pragma unroll
      for (int im = 0; im < 4; ++im)
        fa[im] = *(const bf16x8*)(As + (ar + im * 16) * BK +
                                  (((s * 4 + q) ^ xf) * 8));
#pragma unroll
      for (int j = 0; j < NF; ++j)
        fb[j] = *(const bf16x8*)(Bs + (br + j * 16) * BK +
                                 (((s * 4 + q) ^ xf) * 8));
#pragma unroll
      for (int im = 0; im < 4; ++im)
#pragma unroll
        for (int j = 0; j < NF; ++j)
          acc[im][j] = __builtin_amdgcn_mfma_f32_16x16x32_bf16(
              fa[im], fb[j], acc[im][j], 0, 0, 0);
    }
    __syncthreads();
  }

  // C/D layout: col = lane&15, row = quad*4 + reg (m89/m91-verified).
  const int mBase = m0 + wm * 64 + q * 4;

  if constexpr (MODE == 0) {
    const int sel = n0 >> 10;  // 0=Q 1=K 2=V
    const int nl0 = (n0 & 1023) + wnoff + l16;
    const float* bias = (sel == 0) ? b0 : ((sel == 1) ? b1 : b2);
    const float sc = (sel == 0) ? 0.03125f : 1.0f;  // 1/sqrt(1024) folded into Q
#pragma unroll
    for (int j = 0; j < NF; ++j) {
      const int nl = nl0 + j * 16;
      const float bb = bias[nl];
#pragma unroll
      for (int im = 0; im < 4; ++im) {
        const int mr = mBase + im * 16;
        if (sel < 2) {
          bf16_t* dst = (sel == 0) ? o0 : o1;
#pragma unroll
          for (int r = 0; r < 4; ++r)
            dst[(size_t)(mr + r) * 1024 + nl] =
                (bf16_t)((acc[im][j][r] + bb) * sc);
        } else {
          bf16x4 v;  // V^T[d][key]: 4 regs = 4 consecutive keys -> packed 8B store
#pragma unroll
          for (int r = 0; r < 4; ++r) v[r] = (bf16_t)(acc[im][j][r] + bb);
          *(bf16x4*)(o2 + (size_t)nl * 4096 + mr) = v;
        }
      }
    }
  } else if constexpr (MODE == 1) {
    float ps[4][4];
#pragma unroll
    for (int im = 0; im < 4; ++im)
#pragma unroll
      for (int r = 0; r < 4; ++r) ps[im][r] = 0.f;
#pragma unroll
    for (int j = 0; j < NF; ++j) {
      const int n = n0 + wnoff + j * 16 + l16;
#pragma unroll
      for (int im = 0; im < 4; ++im) {
        const int mr = mBase + im * 16;
#pragma unroll
        for (int r = 0; r < 4; ++r) {
          const float e = __expf(acc[im][j][r]);
          ps[im][r] += e;
          o0[(size_t)(mr + r) * 4096 + n] = (bf16_t)e;
        }
      }
    }
#pragma unroll
    for (int im = 0; im < 4; ++im)
#pragma unroll
      for (int r = 0; r < 4; ++r) {
        float v = ps[im][r];
        v += __shfl_xor(v, 1);
        v += __shfl_xor(v, 2);
        v += __shfl_xor(v, 4);
        v += __shfl_xor(v, 8);
        ps[im][r] = v;
      }
    if (l16 == 0) {
#pragma unroll
      for (int im = 0; im < 4; ++im)
#pragma unroll
        for (int r = 0; r < 4; ++r)
          atomicAdd(rowsum + mBase + im * 16 + r, ps[im][r]);
    }
  } else {
    float inv[4][4];
#pragma unroll
    for (int im = 0; im < 4; ++im)
#pragma unroll
      for (int r = 0; r < 4; ++r)
        inv[im][r] = 1.0f / rowsum[mBase + im * 16 + r];
    if (zz < 3) {  // bf16 partial (normalized); partials over splits sum to O
      bf16_t* pp = (zz == 0) ? o0 : ((zz == 1) ? o1 : o2);
#pragma unroll
      for (int im = 0; im < 4; ++im) {
        const int mr = mBase + im * 16;
#pragma unroll
        for (int j = 0; j < NF; ++j) {
          const int n = n0 + wnoff + j * 16 + l16;
#pragma unroll
          for (int r = 0; r < 4; ++r)
            pp[(size_t)(mr + r) * 1024 + n] =
                (bf16_t)(acc[im][j][r] * inv[im][r]);
        }
      }
    } else {  // z==3: fp32 partial straight into d_out; reduce adds the rest
#pragma unroll
      for (int im = 0; im < 4; ++im) {
        const int mr = mBase + im * 16;
#pragma unroll
        for (int j = 0; j < NF; ++j) {
          const int n = n0 + wnoff + j * 16 + l16;
#pragma unroll
          for (int r = 0; r < 4; ++r)
            fout[(size_t)(mr + r) * 1024 + n] = acc[im][j][r] * inv[im][r];
        }
      }
    }
  }
}

// Converts X|Wq|Wk|Wv to bf16; last 16 blocks zero rowsum (4096 f32).
__global__ __launch_bounds__(256) void cvt_all(
    const float* __restrict__ X, const float* __restrict__ Wq,
    const float* __restrict__ Wk, const float* __restrict__ Wv,
    bf16_t* __restrict__ Xb, bf16_t* __restrict__ Wb,
    float* __restrict__ rowsum) {
  int i = blockIdx.x * 256 + threadIdx.x;  // float4 index
  if (i >= 1835008) {                      // 7168 blocks of cvt work
    rowsum[i - 1835008] = 0.f;             // 16 blocks x 256 = 4096 floats
    return;
  }
  const float* src;
  bf16_t* dst;
  int off;
  if (i < 1048576) {
    src = X; dst = Xb; off = i;
  } else {
    const int w = i - 1048576;
    const int sel = w >> 18;
    off = w & 0x3FFFF;
    src = (sel == 0) ? Wq : ((sel == 1) ? Wk : Wv);
    dst = Wb + (size_t)sel * (1024 * 1024);
  }
  const float4 v = ((const float4*)src)[off];
  bf16x4 o;
  o[0] = (bf16_t)v.x; o[1] = (bf16_t)v.y; o[2] = (bf16_t)v.z; o[3] = (bf16_t)v.w;
  ((bf16x4*)dst)[off] = o;
}

// out[i] += f32(p0[i]) + f32(p1[i]) + f32(p2[i]);  8 elems/thread.
__global__ __launch_bounds__(256) void reduce_out(
    const bf16_t* __restrict__ p0, const bf16_t* __restrict__ p1,
    const bf16_t* __restrict__ p2, float* __restrict__ out) {
  const int i = blockIdx.x * 256 + threadIdx.x;  // bf16x8 index
  const bf16x8 a = ((const bf16x8*)p0)[i];
  const bf16x8 b = ((const bf16x8*)p1)[i];
  const bf16x8 c = ((const bf16x8*)p2)[i];
  float4 lo = ((const float4*)out)[2 * i];
  float4 hi = ((const float4*)out)[2 * i + 1];
  lo.x += (float)a[0] + (float)b[0] + (float)c[0];
  lo.y += (float)a[1] + (float)b[1] + (float)c[1];
  lo.z += (float)a[2] + (float)b[2] + (float)c[2];
  lo.w += (float)a[3] + (float)b[3] + (float)c[3];
  hi.x += (float)a[4] + (float)b[4] + (float)c[4];
  hi.y += (float)a[5] + (float)b[5] + (float)c[5];
  hi.z += (float)a[6] + (float)b[6] + (float)c[6];
  hi.w += (float)a[7] + (float)b[7] + (float)c[7];
  ((float4*)out)[2 * i] = lo;
  ((float4*)out)[2 * i + 1] = hi;
}

extern "C" void kernel_launch(void* const* d_in, const int* in_sizes, int n_in,
                              void* d_out, int out_size, void* d_ws,
                              size_t ws_size, hipStream_t stream) {
  const int S = 4096, D = 1024;
  const float* X  = (const float*)d_in[0];
  const float* Wq = (const float*)d_in[1];
  const float* bq = (const float*)d_in[2];
  const float* Wk = (const float*)d_in[3];
  const float* bk = (const float*)d_in[4];
  const float* Wv = (const float*)d_in[5];
  const float* bv = (const float*)d_in[6];
  float* out = (float*)d_out;

  // ws layout (70 MB bf16 + 16 KB fp32). G3 split-K=4 partials reuse dead
  // regions: Xb (dead after G1), Qb, Kb (dead after G2); z=3 goes to d_out.
  bf16_t* Xb = (bf16_t*)d_ws;            // [4096][1024]
  bf16_t* Wb = Xb + (size_t)S * D;       // [3072][1024]
  bf16_t* Qb = Wb + (size_t)3 * D * D;   // [4096][1024], pre-scaled by 1/32
  bf16_t* Kb = Qb + (size_t)S * D;       // [4096][1024]
  bf16_t* Vt = Kb + (size_t)S * D;       // [1024][4096]  V transposed
  bf16_t* Sc = Vt + (size_t)D * S;       // [4096][4096]  exp(scores)
  float* rowsum = (float*)(Sc + (size_t)S * S);  // [4096]

  cvt_all<<<7184, 256, 0, stream>>>(X, Wq, Wk, Wv, Xb, Wb, rowsum);

  // G1: QKV = Xb @ Wb^T + bias  (M=4096, N=3072, K=1024), BK=64, grid 768 (3/CU)
  gemm_k<0, 128, 64><<<dim3(3 * D / 128, S / 128), 256, 0, stream>>>(
      Xb, Wb, D, D, Qb, Kb, Vt, bq, bk, bv, nullptr, nullptr);
  // G2: Sc = exp(Qb @ Kb^T), rowsum partials  (M=N=4096, K=1024), BK=64, grid 1024
  gemm_k<1, 128, 64><<<dim3(S / 128, S / 128), 256, 0, stream>>>(
      Qb, Kb, D, D, Sc, nullptr, nullptr, nullptr, nullptr, nullptr, nullptr,
      rowsum);
  // G3: O-partials = (Sc @ Vt^T)/rowsum, K split 4x1024, 1D grid 1024, XCD decode
  gemm_k<2, 128, 64><<<1024, 256, 0, stream>>>(
      Sc, Vt, S, S / 4, Xb, Qb, Kb, nullptr, nullptr, nullptr, out, rowsum);
  // out += p0 + p1 + p2
  reduce_out<<<S * D / 8 / 256, 256, 0, stream>>>(Xb, Qb, Kb, out);
}